// Round 10
// baseline (118.603 us; speedup 1.0000x reference)
//
#include <hip/hip_runtime.h>
#include <math.h>

#define B_N   32768
#define SD    5
#define MD    4
#define HID   128
#define NH    64
#define NSIG  11
#define DT    0.01f

#define IDX(i, j) ((i) * ((i) + 1) / 2 + (j))

typedef _Float16 h2v  __attribute__((ext_vector_type(2)));
typedef float    f32x4 __attribute__((ext_vector_type(4)));

#define CONST_AS __attribute__((address_space(4)))

// wave-uniform scalar load path (s_load_dwordx4)
__device__ __forceinline__ f32x4 ldc4(const float* p) {
    return *(const CONST_AS f32x4*)(uintptr_t)p;
}

__device__ __forceinline__ float fexp2(float x) {
#if __has_builtin(__builtin_amdgcn_exp2f)
    return __builtin_amdgcn_exp2f(x);
#else
    return exp2f(x);
#endif
}

__device__ __forceinline__ float fexp(float x) {
    return fexp2(x * 1.4426950408889634f);
}

__device__ __forceinline__ float packh2(float a, float b) {
    union { h2v h; float f; } u;
    u.h.x = (_Float16)a; u.h.y = (_Float16)b;
    return u.f;
}

// ---- true VOP3P packed-f16 via inline asm (carrier = 32-bit float) ----
__device__ __forceinline__ float pk_fma_vs(float a, float b_s, float c) {
    float d;
    asm("v_pk_fma_f16 %0, %1, %2, %3" : "=v"(d) : "v"(a), "s"(b_s), "v"(c));
    return d;
}
__device__ __forceinline__ float pk_fma_vv(float a, float b, float c) {
    float d;
    asm("v_pk_fma_f16 %0, %1, %2, %3" : "=v"(d) : "v"(a), "v"(b), "v"(c));
    return d;
}
__device__ __forceinline__ float pk_mul(float a, float b) {
    float d;
    asm("v_pk_mul_f16 %0, %1, %2" : "=v"(d) : "v"(a), "v"(b));
    return d;
}
__device__ __forceinline__ float pk_max(float a, float b) {
    float d;
    asm("v_pk_max_f16 %0, %1, %2" : "=v"(d) : "v"(a), "v"(b));
    return d;
}
__device__ __forceinline__ float pk_min(float a, float b) {
    float d;
    asm("v_pk_min_f16 %0, %1, %2" : "=v"(d) : "v"(a), "v"(b));
    return d;
}

// f32 odd order-9 polynomial tanh, clamped to [-3,3] (noise MLP path)
__device__ __forceinline__ float tpoly(float x) {
#if __has_builtin(__builtin_amdgcn_fmed3f)
    float p = __builtin_amdgcn_fmed3f(x, -3.0f, 3.0f);
#else
    float p = fminf(fmaxf(x, -3.0f), 3.0f);
#endif
    float u = p * p;
    float h = fmaf(u, 0.000412619f, -0.00901606f);
    h = fmaf(u, h, 0.07293188f);
    h = fmaf(u, h, -0.30093534f);
    h = fmaf(u, h, 0.9982018f);
    return p * h;
}

// ---- prep (layouts unchanged from R9) ----
__global__ void ukf_prep(const float* __restrict__ W1, const float* __restrict__ b1,
                         const float* __restrict__ W2,
                         const float* __restrict__ Wn1, const float* __restrict__ bn1,
                         const float* __restrict__ Wq, const float* __restrict__ Wr,
                         float* __restrict__ wpk, float* __restrict__ wnk) {
    const int p = threadIdx.x;
    if (p < 64) {
        const int k0 = 2 * p, k1 = 2 * p + 1;
        float* o = wpk + p * 16;
#pragma unroll
        for (int i = 0; i < 7; ++i) o[i] = packh2(W1[i * HID + k0], W1[i * HID + k1]);
        o[7] = packh2(b1[k0], b1[k1]);
#pragma unroll
        for (int j = 0; j < 7; ++j) o[8 + j] = packh2(W2[k0 * 7 + j], W2[k1 * 7 + j]);
        o[15] = 0.0f;
    } else if (p < 128) {
        const int k = p - 64;
        float* o = wnk + k * 16;
#pragma unroll
        for (int i = 0; i < 5; ++i) o[i] = Wn1[i * NH + k];
        o[5] = bn1[k];
#pragma unroll
        for (int j = 0; j < 5; ++j) o[6 + j] = Wq[k * 5 + j];
#pragma unroll
        for (int j = 0; j < 4; ++j) o[11 + j] = Wr[k * 4 + j];
        o[15] = 0.0f;
    }
}

// MLP dynamics, true packed-f16 pairs; weights via wave-uniform s_load.
__device__ __forceinline__ void dyn_eval(const float* __restrict__ wpk,
                                         const float* __restrict__ b2r,
                                         const float* __restrict__ z,
                                         float* __restrict__ out) {
    float zb[7];
#pragma unroll
    for (int i = 0; i < 7; ++i) zb[i] = packh2(z[i], z[i]);

    const float PHIc = packh2(3.0f, 3.0f);
    const float PLOc = packh2(-3.0f, -3.0f);
    const float C4c  = packh2(0.000412619f, 0.000412619f);
    const float C3c  = packh2(-0.00901606f, -0.00901606f);
    const float C2c  = packh2(0.07293188f, 0.07293188f);
    const float C1c  = packh2(-0.30093534f, -0.30093534f);
    const float C0c  = packh2(0.9982018f, 0.9982018f);

    float acc[7];
#pragma unroll
    for (int j = 0; j < 7; ++j) acc[j] = 0.0f;   // (0h,0h)

#pragma unroll 4
    for (int p = 0; p < 64; ++p) {
        const float* row = wpk + (p << 4);
        f32x4 wa = ldc4(row);
        f32x4 wb = ldc4(row + 4);
        f32x4 wc = ldc4(row + 8);
        f32x4 wd = ldc4(row + 12);
        float bias = wb.w;                       // (b1[k0], b1[k1]) -> VGPR
        float pre = pk_fma_vs(zb[0], wa.x, bias);
        pre = pk_fma_vs(zb[1], wa.y, pre);
        pre = pk_fma_vs(zb[2], wa.z, pre);
        pre = pk_fma_vs(zb[3], wa.w, pre);
        pre = pk_fma_vs(zb[4], wb.x, pre);
        pre = pk_fma_vs(zb[5], wb.y, pre);
        pre = pk_fma_vs(zb[6], wb.z, pre);
        // packed poly tanh
        float pc = pk_min(pk_max(pre, PLOc), PHIc);
        float u = pk_mul(pc, pc);
        float h = pk_fma_vv(u, C4c, C3c);
        h = pk_fma_vv(u, h, C2c);
        h = pk_fma_vv(u, h, C1c);
        h = pk_fma_vv(u, h, C0c);
        float tt = pk_mul(pc, h);
        acc[0] = pk_fma_vs(tt, wc.x, acc[0]);
        acc[1] = pk_fma_vs(tt, wc.y, acc[1]);
        acc[2] = pk_fma_vs(tt, wc.z, acc[2]);
        acc[3] = pk_fma_vs(tt, wc.w, acc[3]);
        acc[4] = pk_fma_vs(tt, wd.x, acc[4]);
        acc[5] = pk_fma_vs(tt, wd.y, acc[5]);
        acc[6] = pk_fma_vs(tt, wd.z, acc[6]);
    }
#pragma unroll
    for (int j = 0; j < 7; ++j) {
        union { float f; h2v h; } u2; u2.f = acc[j];
        out[j] = b2r[j] + (float)u2.h.x + (float)u2.h.y;
    }
}

// block = 704 threads; tid = s*64 + e (wave <-> sigma index, uniform s).
// Stage 0: coalesced global->LDS staging of P/X/u/y.
// Stage 1: wave 0 computes per-element Cholesky once -> LDS.
// Stage 2: Euler step per sigma point + distributed noise-MLP partials.
// Stage 3: wave 0 does moments + update, stages outputs to LDS.
// Stage 4: all threads write outputs coalesced.
__global__ __launch_bounds__(704) void ukf_main(
    const float* __restrict__ Xh, const float* __restrict__ Pin,
    const float* __restrict__ Uin, const float* __restrict__ Yin,
    const float* __restrict__ b2g, const float* __restrict__ bqg,
    const float* __restrict__ brg, const float* __restrict__ Hg,
    const float* __restrict__ wpk, const float* __restrict__ wnk,
    float* __restrict__ out) {
    __shared__ float sP[64 * 25];     // staged P (stride 25, coprime 32)
    __shared__ float sx[64 * 5];      // staged X_hat
    __shared__ float su[64 * 2];      // staged u
    __shared__ float sy[64 * 4];      // staged y
    __shared__ float sL[64 * 15];     // cholesky (stride 15, coprime 32)
    __shared__ float spts[64 * 55];   // [elem][sig][5]
    __shared__ float pn[64 * 99];     // [elem][sig][9]
    __shared__ float so[64 * 33];     // staged outputs (stride 33)

    const int tid = threadIdx.x;
    const int s = tid >> 6;           // wave index = sigma index (uniform)
    const int e = tid & 63;
    const int base = blockIdx.x * 64;

    // ---- stage 0: coalesced loads ----
    for (int idx = tid; idx < 64 * 25; idx += 704) sP[idx] = Pin[base * 25 + idx];
    for (int idx = tid; idx < 64 * 5;  idx += 704) sx[idx] = Xh[base * 5 + idx];
    for (int idx = tid; idx < 64 * 2;  idx += 704) su[idx] = Uin[base * 2 + idx];
    for (int idx = tid; idx < 64 * 4;  idx += 704) sy[idx] = Yin[base * 4 + idx];
    __syncthreads();

    // ---- stage 1: Cholesky of 3*P, once per element (wave 0) ----
    if (tid < 64) {
        float L[15];
#pragma unroll
        for (int i = 0; i < SD; ++i)
#pragma unroll
            for (int j = 0; j <= i; ++j)
                L[IDX(i, j)] = 3.0f * sP[tid * 25 + i * 5 + j];
#pragma unroll
        for (int j = 0; j < SD; ++j) {
            float d = L[IDX(j, j)];
#pragma unroll
            for (int k = 0; k < j; ++k) { float l = L[IDX(j, k)]; d = fmaf(-l, l, d); }
            d = sqrtf(d);
            L[IDX(j, j)] = d;
            float inv = 1.0f / d;
#pragma unroll
            for (int i = j + 1; i < SD; ++i) {
                float v = L[IDX(i, j)];
#pragma unroll
                for (int k = 0; k < j; ++k) v = fmaf(-L[IDX(i, k)], L[IDX(j, k)], v);
                L[IDX(i, j)] = v * inv;
            }
        }
#pragma unroll
        for (int t = 0; t < 15; ++t) sL[tid * 15 + t] = L[t];
    }
    __syncthreads();

    float b2r[7];
#pragma unroll
    for (int j = 0; j < 7; ++j) b2r[j] = b2g[j];

    float x[SD];
#pragma unroll
    for (int i = 0; i < SD; ++i) x[i] = sx[e * 5 + i];

    float z[7];
#pragma unroll
    for (int i = 0; i < SD; ++i) z[i] = x[i];
    z[5] = su[e * 2 + 0];
    z[6] = su[e * 2 + 1];
    {
        const int c = (s >= 6) ? (s - 6) : (s - 1);   // -1 when s==0 (wave-uniform)
        const float sgn = (s >= 6) ? -1.0f : 1.0f;
        if (c >= 0) {
#pragma unroll
            for (int cc = 0; cc < SD; ++cc) {
                if (cc == c) {
#pragma unroll
                    for (int i = cc; i < SD; ++i)
                        z[i] = fmaf(sgn, sL[e * 15 + IDX(i, cc)], z[i]);
                }
            }
        }
    }

    // ---- stage 2: Euler step + distributed noise-MLP partials ----
    float kc[7];
    dyn_eval(wpk, b2r, z, kc);
#pragma unroll
    for (int i = 0; i < SD; ++i)
        spts[e * 55 + s * 5 + i] = fmaf(DT, kc[i], z[i]);

    {
        float gqp[5] = {0.f, 0.f, 0.f, 0.f, 0.f};
        float grp[4] = {0.f, 0.f, 0.f, 0.f};
        const int kbeg = 6 * s;
        const int kend = (kbeg + 6 < NH) ? kbeg + 6 : NH;
        for (int k = kbeg; k < kend; ++k) {       // wave-uniform -> s_load
            const float* row = wnk + (k << 4);
            f32x4 wa = ldc4(row);
            f32x4 wb = ldc4(row + 4);
            f32x4 wc = ldc4(row + 8);
            f32x4 wd = ldc4(row + 12);
            float pre = wb.y;                     // bn1[k]
            pre = fmaf(x[0], wa.x, pre);
            pre = fmaf(x[1], wa.y, pre);
            pre = fmaf(x[2], wa.z, pre);
            pre = fmaf(x[3], wa.w, pre);
            pre = fmaf(x[4], wb.x, pre);
            float t = tpoly(pre);
            gqp[0] = fmaf(t, wb.z, gqp[0]);
            gqp[1] = fmaf(t, wb.w, gqp[1]);
            gqp[2] = fmaf(t, wc.x, gqp[2]);
            gqp[3] = fmaf(t, wc.y, gqp[3]);
            gqp[4] = fmaf(t, wc.z, gqp[4]);
            grp[0] = fmaf(t, wc.w, grp[0]);
            grp[1] = fmaf(t, wd.x, grp[1]);
            grp[2] = fmaf(t, wd.y, grp[2]);
            grp[3] = fmaf(t, wd.z, grp[3]);
        }
        float* pp = pn + e * 99 + s * 9;
#pragma unroll
        for (int r = 0; r < 5; ++r) pp[r] = gqp[r];
#pragma unroll
        for (int r = 0; r < 4; ++r) pp[5 + r] = grp[r];
    }

    __syncthreads();

    // ---- stage 3: one thread per element (wave 0) ----
    if (tid < 64) {
        float xp[SD], M[15];
#pragma unroll
        for (int i = 0; i < SD; ++i) xp[i] = 0.0f;
#pragma unroll
        for (int i = 0; i < 15; ++i) M[i] = 0.0f;
#pragma unroll
        for (int si = 0; si < NSIG; ++si) {
            const float w = (si == 0) ? (-2.0f / 3.0f) : (1.0f / 6.0f);
            float p[SD];
#pragma unroll
            for (int i = 0; i < SD; ++i) p[i] = spts[tid * 55 + si * 5 + i];
#pragma unroll
            for (int i = 0; i < SD; ++i) xp[i] = fmaf(w, p[i], xp[i]);
#pragma unroll
            for (int i = 0; i < SD; ++i)
#pragma unroll
                for (int j = 0; j <= i; ++j)
                    M[IDX(i, j)] = fmaf(w * p[i], p[j], M[IDX(i, j)]);
        }
        float Pp[15];
#pragma unroll
        for (int i = 0; i < SD; ++i)
#pragma unroll
            for (int j = 0; j <= i; ++j)
                Pp[IDX(i, j)] = fmaf(-xp[i], xp[j], M[IDX(i, j)]);

        // reduce noise-MLP partials
        float gq[5], gr[4];
#pragma unroll
        for (int j = 0; j < 5; ++j) gq[j] = bqg[j];
#pragma unroll
        for (int j = 0; j < 4; ++j) gr[j] = brg[j];
#pragma unroll
        for (int si = 0; si < NSIG; ++si) {
            const float* pp = pn + tid * 99 + si * 9;
#pragma unroll
            for (int r = 0; r < 5; ++r) gq[r] += pp[r];
#pragma unroll
            for (int r = 0; r < 4; ++r) gr[r] += pp[5 + r];
        }

        const float ent0 = 7.0946927f + 0.5f * (gq[0] + gq[1] + gq[2] + gq[3] + gq[4]);
        const float logscale = fmaxf(7.1f - ent0, 0.0f) * 0.2f;
        const float entQ = fmaf(2.5f, logscale, ent0);
        const float entR = 5.6757541f + 0.5f * (gr[0] + gr[1] + gr[2] + gr[3]);
        float qd[5], rd[4];
#pragma unroll
        for (int j = 0; j < 5; ++j) qd[j] = fexp(gq[j] + logscale);
#pragma unroll
        for (int j = 0; j < 4; ++j) rd[j] = fexp(gr[j]);

#pragma unroll
        for (int j = 0; j < SD; ++j) Pp[IDX(j, j)] += qd[j];

        // ------- exact linear update: S = H5^T Pp H5 + R, Pxy = Pp H5 -------
        float Hh[7][4];
#pragma unroll
        for (int i = 0; i < 7; ++i)
#pragma unroll
            for (int m = 0; m < 4; ++m) Hh[i][m] = Hg[i * 4 + m];

        const float uu0 = su[tid * 2 + 0];
        const float uu1 = su[tid * 2 + 1];
        float yv[4];
#pragma unroll
        for (int m = 0; m < 4; ++m) yv[m] = sy[tid * 4 + m];

        float yh[4];
#pragma unroll
        for (int m = 0; m < 4; ++m) {
            float v = fmaf(uu0, Hh[5][m], uu1 * Hh[6][m]);
#pragma unroll
            for (int i = 0; i < SD; ++i) v = fmaf(xp[i], Hh[i][m], v);
            yh[m] = v;
        }

        float Pxy[5][4];
#pragma unroll
        for (int i = 0; i < SD; ++i)
#pragma unroll
            for (int m = 0; m < 4; ++m) {
                float v = 0.0f;
#pragma unroll
                for (int j = 0; j < SD; ++j) {
                    float pij = (i >= j) ? Pp[IDX(i, j)] : Pp[IDX(j, i)];
                    v = fmaf(pij, Hh[j][m], v);
                }
                Pxy[i][m] = v;
            }

        float Sm[10];
#pragma unroll
        for (int m = 0; m < 4; ++m)
#pragma unroll
            for (int n = 0; n <= m; ++n) {
                float v = 0.0f;
#pragma unroll
                for (int i = 0; i < SD; ++i) v = fmaf(Hh[i][m], Pxy[i][n], v);
                Sm[IDX(m, n)] = v;
            }
#pragma unroll
        for (int m = 0; m < 4; ++m) Sm[IDX(m, m)] += rd[m];

        // Cholesky of S (4x4, packed lower)
        float Ls[10], di[4];
#pragma unroll
        for (int m = 0; m < 4; ++m) {
            float d = Sm[IDX(m, m)];
#pragma unroll
            for (int k = 0; k < m; ++k) { float l = Ls[IDX(m, k)]; d = fmaf(-l, l, d); }
            d = sqrtf(d);
            Ls[IDX(m, m)] = d;
            di[m] = 1.0f / d;
#pragma unroll
            for (int n = m + 1; n < 4; ++n) {
                float v = Sm[IDX(n, m)];
#pragma unroll
                for (int k = 0; k < m; ++k) v = fmaf(-Ls[IDX(n, k)], Ls[IDX(m, k)], v);
                Ls[IDX(n, m)] = v * di[m];
            }
        }

        // K = Pxy S^{-1}
        float K[5][4];
#pragma unroll
        for (int i = 0; i < SD; ++i) {
            float w[4];
#pragma unroll
            for (int m = 0; m < 4; ++m) {
                float v = Pxy[i][m];
#pragma unroll
                for (int k = 0; k < m; ++k) v = fmaf(-Ls[IDX(m, k)], w[k], v);
                w[m] = v * di[m];
            }
#pragma unroll
            for (int m = 3; m >= 0; --m) {
                float v = w[m];
#pragma unroll
                for (int k = m + 1; k < 4; ++k) v = fmaf(-Ls[IDX(k, m)], K[i][k], v);
                K[i][m] = v * di[m];
            }
        }

        float inn[4];
#pragma unroll
        for (int m = 0; m < 4; ++m) inn[m] = yv[m] - yh[m];

        float Xn[5];
#pragma unroll
        for (int i = 0; i < SD; ++i) {
            float v = xp[i];
#pragma unroll
            for (int m = 0; m < 4; ++m) v = fmaf(K[i][m], inn[m], v);
            Xn[i] = v;
        }

        // P_new = Pp - (K S) K^T
        float KS[5][4];
#pragma unroll
        for (int i = 0; i < SD; ++i)
#pragma unroll
            for (int m = 0; m < 4; ++m) {
                float v = 0.0f;
#pragma unroll
                for (int n = 0; n < 4; ++n) {
                    float snm = (n >= m) ? Sm[IDX(n, m)] : Sm[IDX(m, n)];
                    v = fmaf(K[i][n], snm, v);
                }
                KS[i][m] = v;
            }
        float Pn[15];
#pragma unroll
        for (int i = 0; i < SD; ++i)
#pragma unroll
            for (int j = 0; j <= i; ++j) {
                float v = Pp[IDX(i, j)];
#pragma unroll
                for (int m = 0; m < 4; ++m) v = fmaf(-KS[i][m], K[j][m], v);
                Pn[IDX(i, j)] = v;
            }

        // stage outputs into LDS (stride 33 to spread banks)
        float* o = so + tid * 33;
#pragma unroll
        for (int i = 0; i < SD; ++i) o[i] = Xn[i];
#pragma unroll
        for (int i = 0; i < SD; ++i)
#pragma unroll
            for (int j = 0; j < SD; ++j)
                o[5 + i * 5 + j] = (i >= j) ? Pn[IDX(i, j)] : Pn[IDX(j, i)];
        o[30] = entQ;
        o[31] = entR;
    }

    __syncthreads();

    // ---- stage 4: coalesced output writes ----
    for (int idx = tid; idx < 64 * 5; idx += 704) {
        const int ee = idx / 5, cc = idx - ee * 5;
        out[base * 5 + idx] = so[ee * 33 + cc];
    }
    for (int idx = tid; idx < 64 * 25; idx += 704) {
        const int ee = idx / 25, cc = idx - ee * 25;
        out[B_N * 5 + base * 25 + idx] = so[ee * 33 + 5 + cc];
    }
    if (tid < 64) {
        out[B_N * 30 + base + tid] = so[tid * 33 + 30];
        out[B_N * 31 + base + tid] = so[tid * 33 + 31];
    }
}

extern "C" void kernel_launch(void* const* d_in, const int* in_sizes, int n_in,
                              void* d_out, int out_size, void* d_ws, size_t ws_size,
                              hipStream_t stream) {
    const float* Xh  = (const float*)d_in[0];
    const float* P   = (const float*)d_in[1];
    const float* u   = (const float*)d_in[2];
    const float* y   = (const float*)d_in[3];
    const float* W1  = (const float*)d_in[4];
    const float* b1  = (const float*)d_in[5];
    const float* W2  = (const float*)d_in[6];
    const float* b2  = (const float*)d_in[7];
    const float* Wn1 = (const float*)d_in[8];
    const float* bn1 = (const float*)d_in[9];
    const float* Wq  = (const float*)d_in[10];
    const float* bq  = (const float*)d_in[11];
    const float* Wr  = (const float*)d_in[12];
    const float* br  = (const float*)d_in[13];
    const float* Hob = (const float*)d_in[14];

    float* wpk = (float*)d_ws;           // 64 pair-rows * 16 floats = 4 KB
    float* wnk = wpk + 64 * 16;          // 64 unit-rows * 16 floats = 4 KB

    ukf_prep<<<1, 128, 0, stream>>>(W1, b1, W2, Wn1, bn1, Wq, Wr, wpk, wnk);
    ukf_main<<<B_N / 64, 704, 0, stream>>>(Xh, P, u, y, b2, bq, br, Hob,
                                           wpk, wnk, (float*)d_out);
}

// Round 11
// 99.011 us; speedup vs baseline: 1.1979x; 1.1979x over previous
//
#include <hip/hip_runtime.h>
#include <math.h>

#define B_N   32768
#define SD    5
#define MD    4
#define HID   128
#define NH    64
#define DT    0.01f

#define IDX(i, j) ((i) * ((i) + 1) / 2 + (j))

typedef _Float16 h2v  __attribute__((ext_vector_type(2)));
typedef float    f32x4 __attribute__((ext_vector_type(4)));

#define CONST_AS __attribute__((address_space(4)))

// wave-uniform scalar load path (s_load_dwordx4)
__device__ __forceinline__ f32x4 ldc4(const float* p) {
    return *(const CONST_AS f32x4*)(uintptr_t)p;
}

__device__ __forceinline__ float fexp2(float x) {
#if __has_builtin(__builtin_amdgcn_exp2f)
    return __builtin_amdgcn_exp2f(x);
#else
    return exp2f(x);
#endif
}

__device__ __forceinline__ float fexp(float x) {
    return fexp2(x * 1.4426950408889634f);
}

__device__ __forceinline__ float packh2(float a, float b) {
    union { h2v h; float f; } u;
    u.h.x = (_Float16)a; u.h.y = (_Float16)b;
    return u.f;
}
__device__ __forceinline__ float unpk_lo(float f) {
    union { float f; h2v h; } u; u.f = f; return (float)u.h.x;
}
__device__ __forceinline__ float unpk_hi(float f) {
    union { float f; h2v h; } u; u.f = f; return (float)u.h.y;
}
// packed f16 negate via sign-bit xor (no asm-modifier risk)
__device__ __forceinline__ float pk_neg(float f) {
    union { float f; unsigned u; } x; x.f = f; x.u ^= 0x80008000u; return x.f;
}

// ---- true VOP3P packed-f16 via inline asm (carrier = 32-bit float) ----
__device__ __forceinline__ float pk_fma_vs(float a, float b_s, float c) {
    float d;
    asm("v_pk_fma_f16 %0, %1, %2, %3" : "=v"(d) : "v"(a), "s"(b_s), "v"(c));
    return d;
}
__device__ __forceinline__ float pk_fma_vv(float a, float b, float c) {
    float d;
    asm("v_pk_fma_f16 %0, %1, %2, %3" : "=v"(d) : "v"(a), "v"(b), "v"(c));
    return d;
}
__device__ __forceinline__ float pk_mul(float a, float b) {
    float d;
    asm("v_pk_mul_f16 %0, %1, %2" : "=v"(d) : "v"(a), "v"(b));
    return d;
}
__device__ __forceinline__ float pk_mul_vs(float a, float b_s) {
    float d;
    asm("v_pk_mul_f16 %0, %1, %2" : "=v"(d) : "v"(a), "s"(b_s));
    return d;
}
__device__ __forceinline__ float pk_add(float a, float b) {
    float d;
    asm("v_pk_add_f16 %0, %1, %2" : "=v"(d) : "v"(a), "v"(b));
    return d;
}
__device__ __forceinline__ float pk_max(float a, float b) {
    float d;
    asm("v_pk_max_f16 %0, %1, %2" : "=v"(d) : "v"(a), "v"(b));
    return d;
}
__device__ __forceinline__ float pk_min(float a, float b) {
    float d;
    asm("v_pk_min_f16 %0, %1, %2" : "=v"(d) : "v"(a), "v"(b));
    return d;
}

// packed poly tanh on f16 pairs (carrier floats); returns tt = tanh(pre)
__device__ __forceinline__ float pk_tanh(float pre) {
    const float PHIc = packh2(3.0f, 3.0f);
    const float PLOc = packh2(-3.0f, -3.0f);
    const float C4c  = packh2(0.000412619f, 0.000412619f);
    const float C3c  = packh2(-0.00901606f, -0.00901606f);
    const float C2c  = packh2(0.07293188f, 0.07293188f);
    const float C1c  = packh2(-0.30093534f, -0.30093534f);
    const float C0c  = packh2(0.9982018f, 0.9982018f);
    float pc = pk_min(pk_max(pre, PLOc), PHIc);
    float u = pk_mul(pc, pc);
    float h = pk_fma_vv(u, C4c, C3c);
    h = pk_fma_vv(u, h, C2c);
    h = pk_fma_vv(u, h, C1c);
    h = pk_fma_vv(u, h, C0c);
    return pk_mul(pc, h);
}

// ---- prep ----
// wpk: 64 pair-rows x 16 floats (packed half2 over units k0=2p,k1=2p+1):
//   [0..6]=(W1[i][k0],W1[i][k1]) i=0..6, [7]=(b1 pair), [8..14]=(W2[k][j] pairs) j=0..6
// wnk: 32 pair-rows x 16 floats (packed half2):
//   [0..4]=(Wn1[i] pairs) i=0..4, [5]=(bn1 pair), [6..10]=(Wq[k][j] pairs), [11..14]=(Wr pairs)
__global__ void ukf_prep(const float* __restrict__ W1, const float* __restrict__ b1,
                         const float* __restrict__ W2,
                         const float* __restrict__ Wn1, const float* __restrict__ bn1,
                         const float* __restrict__ Wq, const float* __restrict__ Wr,
                         float* __restrict__ wpk, float* __restrict__ wnk) {
    const int p = threadIdx.x;
    if (p < 64) {
        const int k0 = 2 * p, k1 = 2 * p + 1;
        float* o = wpk + p * 16;
#pragma unroll
        for (int i = 0; i < 7; ++i) o[i] = packh2(W1[i * HID + k0], W1[i * HID + k1]);
        o[7] = packh2(b1[k0], b1[k1]);
#pragma unroll
        for (int j = 0; j < 7; ++j) o[8 + j] = packh2(W2[k0 * 7 + j], W2[k1 * 7 + j]);
        o[15] = 0.0f;
    } else if (p < 96) {
        const int q = p - 64;
        const int k0 = 2 * q, k1 = 2 * q + 1;
        float* o = wnk + q * 16;
#pragma unroll
        for (int i = 0; i < 5; ++i) o[i] = packh2(Wn1[i * NH + k0], Wn1[i * NH + k1]);
        o[5] = packh2(bn1[k0], bn1[k1]);
#pragma unroll
        for (int j = 0; j < 5; ++j) o[6 + j] = packh2(Wq[k0 * 5 + j], Wq[k1 * 5 + j]);
#pragma unroll
        for (int j = 0; j < 4; ++j) o[11 + j] = packh2(Wr[k0 * 4 + j], Wr[k1 * 4 + j]);
        o[15] = 0.0f;
    }
}

// EKF-form UKF step (exact under Euler + sigma-pair symmetry):
//   x_pred = x + DT*f(x);  P_pred = (I + DT*J) P (I + DT*J)^T + Q
// block = 640 threads = 64 elements x 10 waves (role = wave index):
//   roles 0-7 : K-loop quarters (f(x) partials + J partials, packed f16)
//   roles 8-9 : noise-MLP halves (packed f16)
//   role 0 lanes (tid<64): epilogue (reduce, A P A^T, analytic update, writes)
#define PSTR 259   // per-element partial stride (odd -> conflict-free)
__global__ __launch_bounds__(640) void ukf_main(
    const float* __restrict__ Xh, const float* __restrict__ Pin,
    const float* __restrict__ Uin, const float* __restrict__ Yin,
    const float* __restrict__ b2g, const float* __restrict__ bqg,
    const float* __restrict__ brg, const float* __restrict__ Hg,
    const float* __restrict__ wpk, const float* __restrict__ wnk,
    float* __restrict__ out) {
    __shared__ float part[64 * PSTR];   // [elem][8*30 K-partials | 2*9 noise]

    const int tid = threadIdx.x;
    const int role = tid >> 6;        // wave-uniform
    const int e = tid & 63;
    const int bb = blockIdx.x * 64 + e;

    float x[SD];
#pragma unroll
    for (int i = 0; i < SD; ++i) x[i] = Xh[bb * SD + i];

    if (role < 8) {
        // ---- K-loop slice: pair-rows [4*role, 4*role+4) ----
        const float u0 = Uin[bb * 2 + 0];
        const float u1 = Uin[bb * 2 + 1];
        float zb[7];
#pragma unroll
        for (int i = 0; i < SD; ++i) zb[i] = packh2(x[i], x[i]);
        zb[5] = packh2(u0, u0);
        zb[6] = packh2(u1, u1);
        const float ONE2 = packh2(1.0f, 1.0f);

        float fb[5];                  // packed f-bar partials (state dims)
        float J2[25];                 // packed J partials, [i*5+j]
#pragma unroll
        for (int i = 0; i < 5; ++i) fb[i] = 0.0f;
#pragma unroll
        for (int t = 0; t < 25; ++t) J2[t] = 0.0f;

        const int pbeg = role << 2;
#pragma unroll
        for (int pp = 0; pp < 4; ++pp) {
            const float* row = wpk + ((pbeg + pp) << 4);
            f32x4 wa = ldc4(row);
            f32x4 wb = ldc4(row + 4);
            f32x4 wc = ldc4(row + 8);
            f32x4 wd = ldc4(row + 12);
            float pre = pk_fma_vs(zb[0], wa.x, pk_mul_vs(ONE2, wb.w));
            pre = pk_fma_vs(zb[1], wa.y, pre);
            pre = pk_fma_vs(zb[2], wa.z, pre);
            pre = pk_fma_vs(zb[3], wa.w, pre);
            pre = pk_fma_vs(zb[4], wb.x, pre);
            pre = pk_fma_vs(zb[5], wb.y, pre);
            pre = pk_fma_vs(zb[6], wb.z, pre);
            float tt = pk_tanh(pre);
            // f-bar accumulate (state outputs 0..4 = row[8..12])
            fb[0] = pk_fma_vs(tt, wc.x, fb[0]);
            fb[1] = pk_fma_vs(tt, wc.y, fb[1]);
            fb[2] = pk_fma_vs(tt, wc.z, fb[2]);
            fb[3] = pk_fma_vs(tt, wc.w, fb[3]);
            fb[4] = pk_fma_vs(tt, wd.x, fb[4]);
            // g = 1 - t^2  (packed)
            float t2 = pk_mul(tt, tt);
            float g2 = pk_add(ONE2, pk_neg(t2));
            // s_j = g * W1[j][k-pair]  (state inputs j=0..4)
            float s0 = pk_mul_vs(g2, wa.x);
            float s1 = pk_mul_vs(g2, wa.y);
            float s2 = pk_mul_vs(g2, wa.z);
            float s3 = pk_mul_vs(g2, wa.w);
            float s4 = pk_mul_vs(g2, wb.x);
            // J[i][j] += s_j * W2[k][i]
            float w2i[5] = { wc.x, wc.y, wc.z, wc.w, wd.x };
#pragma unroll
            for (int i = 0; i < 5; ++i) {
                J2[i * 5 + 0] = pk_fma_vs(s0, w2i[i], J2[i * 5 + 0]);
                J2[i * 5 + 1] = pk_fma_vs(s1, w2i[i], J2[i * 5 + 1]);
                J2[i * 5 + 2] = pk_fma_vs(s2, w2i[i], J2[i * 5 + 2]);
                J2[i * 5 + 3] = pk_fma_vs(s3, w2i[i], J2[i * 5 + 3]);
                J2[i * 5 + 4] = pk_fma_vs(s4, w2i[i], J2[i * 5 + 4]);
            }
        }
        float* o = part + e * PSTR + role * 30;
#pragma unroll
        for (int i = 0; i < 5; ++i) o[i] = fb[i];
#pragma unroll
        for (int t = 0; t < 25; ++t) o[5 + t] = J2[t];
    } else {
        // ---- noise-MLP slice: pair-rows [16w, 16w+16) ----
        const int w = role - 8;
        float xb[5];
#pragma unroll
        for (int i = 0; i < SD; ++i) xb[i] = packh2(x[i], x[i]);
        const float ONE2 = packh2(1.0f, 1.0f);
        float gq2[5] = {0.f, 0.f, 0.f, 0.f, 0.f};
        float gr2[4] = {0.f, 0.f, 0.f, 0.f};
        const int pbeg = w << 4;
#pragma unroll 4
        for (int pp = 0; pp < 16; ++pp) {
            const float* row = wnk + ((pbeg + pp) << 4);
            f32x4 wa = ldc4(row);
            f32x4 wb = ldc4(row + 4);
            f32x4 wc = ldc4(row + 8);
            f32x4 wd = ldc4(row + 12);
            float pre = pk_fma_vs(xb[0], wa.x, pk_mul_vs(ONE2, wb.y));  // bias [5]
            pre = pk_fma_vs(xb[1], wa.y, pre);
            pre = pk_fma_vs(xb[2], wa.z, pre);
            pre = pk_fma_vs(xb[3], wa.w, pre);
            pre = pk_fma_vs(xb[4], wb.x, pre);
            float tt = pk_tanh(pre);
            gq2[0] = pk_fma_vs(tt, wb.z, gq2[0]);   // Wq j=0 -> [6]
            gq2[1] = pk_fma_vs(tt, wb.w, gq2[1]);
            gq2[2] = pk_fma_vs(tt, wc.x, gq2[2]);
            gq2[3] = pk_fma_vs(tt, wc.y, gq2[3]);
            gq2[4] = pk_fma_vs(tt, wc.z, gq2[4]);
            gr2[0] = pk_fma_vs(tt, wc.w, gr2[0]);   // Wr j=0 -> [11]
            gr2[1] = pk_fma_vs(tt, wd.x, gr2[1]);
            gr2[2] = pk_fma_vs(tt, wd.y, gr2[2]);
            gr2[3] = pk_fma_vs(tt, wd.z, gr2[3]);
        }
        float* o = part + e * PSTR + 240 + w * 9;
#pragma unroll
        for (int r = 0; r < 5; ++r) o[r] = gq2[r];
#pragma unroll
        for (int r = 0; r < 4; ++r) o[5 + r] = gr2[r];
    }

    __syncthreads();

    // ---------------- epilogue: one lane per element (wave 0) ----------------
    if (tid < 64) {
        const float* pe = part + tid * PSTR;

        // reduce K partials (packed adds, then unpack)
        float fb2[5], J2[25];
#pragma unroll
        for (int i = 0; i < 5; ++i) fb2[i] = pe[i];
#pragma unroll
        for (int t = 0; t < 25; ++t) J2[t] = pe[5 + t];
#pragma unroll
        for (int r = 1; r < 8; ++r) {
            const float* pr = pe + r * 30;
#pragma unroll
            for (int i = 0; i < 5; ++i) fb2[i] = pk_add(fb2[i], pr[i]);
#pragma unroll
            for (int t = 0; t < 25; ++t) J2[t] = pk_add(J2[t], pr[5 + t]);
        }

        float xp[SD];
#pragma unroll
        for (int i = 0; i < SD; ++i)
            xp[i] = x[i] + DT * (b2g[i] + unpk_lo(fb2[i]) + unpk_hi(fb2[i]));

        // A = I + DT*J
        float A[5][5];
#pragma unroll
        for (int i = 0; i < 5; ++i)
#pragma unroll
            for (int j = 0; j < 5; ++j)
                A[i][j] = ((i == j) ? 1.0f : 0.0f)
                        + DT * (unpk_lo(J2[i * 5 + j]) + unpk_hi(J2[i * 5 + j]));

        // P_pred = A P A^T
        float Pf[5][5];
#pragma unroll
        for (int i = 0; i < 5; ++i)
#pragma unroll
            for (int j = 0; j < 5; ++j) Pf[i][j] = Pin[bb * 25 + i * 5 + j];
        float T[5][5];
#pragma unroll
        for (int i = 0; i < 5; ++i)
#pragma unroll
            for (int l = 0; l < 5; ++l) {
                float v = 0.0f;
#pragma unroll
                for (int j = 0; j < 5; ++j) v = fmaf(A[i][j], Pf[j][l], v);
                T[i][l] = v;
            }
        float Pp[15];
#pragma unroll
        for (int i = 0; i < 5; ++i)
#pragma unroll
            for (int j = 0; j <= i; ++j) {
                float v = 0.0f;
#pragma unroll
                for (int l = 0; l < 5; ++l) v = fmaf(T[i][l], A[j][l], v);
                Pp[IDX(i, j)] = v;
            }

        // reduce noise partials
        float gq[5], gr[4];
#pragma unroll
        for (int r = 0; r < 5; ++r) {
            float s = pk_add(pe[240 + r], pe[240 + 9 + r]);
            gq[r] = bqg[r] + unpk_lo(s) + unpk_hi(s);
        }
#pragma unroll
        for (int r = 0; r < 4; ++r) {
            float s = pk_add(pe[240 + 5 + r], pe[240 + 14 + r]);
            gr[r] = brg[r] + unpk_lo(s) + unpk_hi(s);
        }

        const float ent0 = 7.0946927f + 0.5f * (gq[0] + gq[1] + gq[2] + gq[3] + gq[4]);
        const float logscale = fmaxf(7.1f - ent0, 0.0f) * 0.2f;
        const float entQ = fmaf(2.5f, logscale, ent0);
        const float entR = 5.6757541f + 0.5f * (gr[0] + gr[1] + gr[2] + gr[3]);
        float qd[5], rd[4];
#pragma unroll
        for (int j = 0; j < 5; ++j) qd[j] = fexp(gq[j] + logscale);
#pragma unroll
        for (int j = 0; j < 4; ++j) rd[j] = fexp(gr[j]);

#pragma unroll
        for (int j = 0; j < SD; ++j) Pp[IDX(j, j)] += qd[j];

        // ------- exact linear update: S = H5^T Pp H5 + R, Pxy = Pp H5 -------
        float Hh[7][4];
#pragma unroll
        for (int i = 0; i < 7; ++i)
#pragma unroll
            for (int m = 0; m < 4; ++m) Hh[i][m] = Hg[i * 4 + m];

        const float uu0 = Uin[bb * 2 + 0];
        const float uu1 = Uin[bb * 2 + 1];
        float yv[4];
#pragma unroll
        for (int m = 0; m < 4; ++m) yv[m] = Yin[bb * 4 + m];

        float yh[4];
#pragma unroll
        for (int m = 0; m < 4; ++m) {
            float v = fmaf(uu0, Hh[5][m], uu1 * Hh[6][m]);
#pragma unroll
            for (int i = 0; i < SD; ++i) v = fmaf(xp[i], Hh[i][m], v);
            yh[m] = v;
        }

        float Pxy[5][4];
#pragma unroll
        for (int i = 0; i < SD; ++i)
#pragma unroll
            for (int m = 0; m < 4; ++m) {
                float v = 0.0f;
#pragma unroll
                for (int j = 0; j < SD; ++j) {
                    float pij = (i >= j) ? Pp[IDX(i, j)] : Pp[IDX(j, i)];
                    v = fmaf(pij, Hh[j][m], v);
                }
                Pxy[i][m] = v;
            }

        float Sm[10];
#pragma unroll
        for (int m = 0; m < 4; ++m)
#pragma unroll
            for (int n = 0; n <= m; ++n) {
                float v = 0.0f;
#pragma unroll
                for (int i = 0; i < SD; ++i) v = fmaf(Hh[i][m], Pxy[i][n], v);
                Sm[IDX(m, n)] = v;
            }
#pragma unroll
        for (int m = 0; m < 4; ++m) Sm[IDX(m, m)] += rd[m];

        // Cholesky of S (4x4, packed lower)
        float Ls[10], di[4];
#pragma unroll
        for (int m = 0; m < 4; ++m) {
            float d = Sm[IDX(m, m)];
#pragma unroll
            for (int k = 0; k < m; ++k) { float l = Ls[IDX(m, k)]; d = fmaf(-l, l, d); }
            d = sqrtf(d);
            Ls[IDX(m, m)] = d;
            di[m] = 1.0f / d;
#pragma unroll
            for (int n = m + 1; n < 4; ++n) {
                float v = Sm[IDX(n, m)];
#pragma unroll
                for (int k = 0; k < m; ++k) v = fmaf(-Ls[IDX(n, k)], Ls[IDX(m, k)], v);
                Ls[IDX(n, m)] = v * di[m];
            }
        }

        // K = Pxy S^{-1}
        float K[5][4];
#pragma unroll
        for (int i = 0; i < SD; ++i) {
            float w[4];
#pragma unroll
            for (int m = 0; m < 4; ++m) {
                float v = Pxy[i][m];
#pragma unroll
                for (int k = 0; k < m; ++k) v = fmaf(-Ls[IDX(m, k)], w[k], v);
                w[m] = v * di[m];
            }
#pragma unroll
            for (int m = 3; m >= 0; --m) {
                float v = w[m];
#pragma unroll
                for (int k = m + 1; k < 4; ++k) v = fmaf(-Ls[IDX(k, m)], K[i][k], v);
                K[i][m] = v * di[m];
            }
        }

        float inn[4];
#pragma unroll
        for (int m = 0; m < 4; ++m) inn[m] = yv[m] - yh[m];

        float Xn[5];
#pragma unroll
        for (int i = 0; i < SD; ++i) {
            float v = xp[i];
#pragma unroll
            for (int m = 0; m < 4; ++m) v = fmaf(K[i][m], inn[m], v);
            Xn[i] = v;
        }

        // P_new = Pp - (K S) K^T
        float KS[5][4];
#pragma unroll
        for (int i = 0; i < SD; ++i)
#pragma unroll
            for (int m = 0; m < 4; ++m) {
                float v = 0.0f;
#pragma unroll
                for (int n = 0; n < 4; ++n) {
                    float snm = (n >= m) ? Sm[IDX(n, m)] : Sm[IDX(m, n)];
                    v = fmaf(K[i][n], snm, v);
                }
                KS[i][m] = v;
            }
        float Pn[15];
#pragma unroll
        for (int i = 0; i < SD; ++i)
#pragma unroll
            for (int j = 0; j <= i; ++j) {
                float v = Pp[IDX(i, j)];
#pragma unroll
                for (int m = 0; m < 4; ++m) v = fmaf(-KS[i][m], K[j][m], v);
                Pn[IDX(i, j)] = v;
            }

#pragma unroll
        for (int i = 0; i < SD; ++i) out[bb * SD + i] = Xn[i];
        float* Po = out + B_N * SD + bb * 25;
#pragma unroll
        for (int i = 0; i < SD; ++i)
#pragma unroll
            for (int j = 0; j < SD; ++j)
                Po[i * 5 + j] = (i >= j) ? Pn[IDX(i, j)] : Pn[IDX(j, i)];
        out[B_N * 30 + bb] = entQ;
        out[B_N * 31 + bb] = entR;
    }
}

extern "C" void kernel_launch(void* const* d_in, const int* in_sizes, int n_in,
                              void* d_out, int out_size, void* d_ws, size_t ws_size,
                              hipStream_t stream) {
    const float* Xh  = (const float*)d_in[0];
    const float* P   = (const float*)d_in[1];
    const float* u   = (const float*)d_in[2];
    const float* y   = (const float*)d_in[3];
    const float* W1  = (const float*)d_in[4];
    const float* b1  = (const float*)d_in[5];
    const float* W2  = (const float*)d_in[6];
    const float* b2  = (const float*)d_in[7];
    const float* Wn1 = (const float*)d_in[8];
    const float* bn1 = (const float*)d_in[9];
    const float* Wq  = (const float*)d_in[10];
    const float* bq  = (const float*)d_in[11];
    const float* Wr  = (const float*)d_in[12];
    const float* br  = (const float*)d_in[13];
    const float* Hob = (const float*)d_in[14];

    float* wpk = (float*)d_ws;           // 64 pair-rows * 16 floats = 4 KB
    float* wnk = wpk + 64 * 16;          // 32 pair-rows * 16 floats = 2 KB

    ukf_prep<<<1, 128, 0, stream>>>(W1, b1, W2, Wn1, bn1, Wq, Wr, wpk, wnk);
    ukf_main<<<B_N / 64, 640, 0, stream>>>(Xh, P, u, y, b2, bq, br, Hob,
                                           wpk, wnk, (float*)d_out);
}

// Round 12
// 95.822 us; speedup vs baseline: 1.2377x; 1.0333x over previous
//
#include <hip/hip_runtime.h>
#include <math.h>

#define B_N   32768
#define SD    5
#define MD    4
#define HID   128
#define NH    64
#define DT    0.01f

#define IDX(i, j) ((i) * ((i) + 1) / 2 + (j))

typedef _Float16 h2v  __attribute__((ext_vector_type(2)));
typedef float    f32x4 __attribute__((ext_vector_type(4)));

__device__ __forceinline__ float fexp2(float x) {
#if __has_builtin(__builtin_amdgcn_exp2f)
    return __builtin_amdgcn_exp2f(x);
#else
    return exp2f(x);
#endif
}

__device__ __forceinline__ float fexp(float x) {
    return fexp2(x * 1.4426950408889634f);
}

__device__ __forceinline__ float packh2(float a, float b) {
    union { h2v h; float f; } u;
    u.h.x = (_Float16)a; u.h.y = (_Float16)b;
    return u.f;
}
__device__ __forceinline__ float unpk_lo(float f) {
    union { float f; h2v h; } u; u.f = f; return (float)u.h.x;
}
__device__ __forceinline__ float unpk_hi(float f) {
    union { float f; h2v h; } u; u.f = f; return (float)u.h.y;
}
// packed f16 negate via sign-bit xor
__device__ __forceinline__ float pk_neg(float f) {
    union { float f; unsigned u; } x; x.f = f; x.u ^= 0x80008000u; return x.f;
}

// ---- true VOP3P packed-f16 via inline asm (carrier = 32-bit float) ----
__device__ __forceinline__ float pk_fma_vv(float a, float b, float c) {
    float d;
    asm("v_pk_fma_f16 %0, %1, %2, %3" : "=v"(d) : "v"(a), "v"(b), "v"(c));
    return d;
}
__device__ __forceinline__ float pk_mul(float a, float b) {
    float d;
    asm("v_pk_mul_f16 %0, %1, %2" : "=v"(d) : "v"(a), "v"(b));
    return d;
}
__device__ __forceinline__ float pk_add(float a, float b) {
    float d;
    asm("v_pk_add_f16 %0, %1, %2" : "=v"(d) : "v"(a), "v"(b));
    return d;
}
__device__ __forceinline__ float pk_max(float a, float b) {
    float d;
    asm("v_pk_max_f16 %0, %1, %2" : "=v"(d) : "v"(a), "v"(b));
    return d;
}
__device__ __forceinline__ float pk_min(float a, float b) {
    float d;
    asm("v_pk_min_f16 %0, %1, %2" : "=v"(d) : "v"(a), "v"(b));
    return d;
}

// packed poly tanh on f16 pairs (carrier floats)
__device__ __forceinline__ float pk_tanh(float pre) {
    const float PHIc = packh2(3.0f, 3.0f);
    const float PLOc = packh2(-3.0f, -3.0f);
    const float C4c  = packh2(0.000412619f, 0.000412619f);
    const float C3c  = packh2(-0.00901606f, -0.00901606f);
    const float C2c  = packh2(0.07293188f, 0.07293188f);
    const float C1c  = packh2(-0.30093534f, -0.30093534f);
    const float C0c  = packh2(0.9982018f, 0.9982018f);
    float pc = pk_min(pk_max(pre, PLOc), PHIc);
    float u = pk_mul(pc, pc);
    float h = pk_fma_vv(u, C4c, C3c);
    h = pk_fma_vv(u, h, C2c);
    h = pk_fma_vv(u, h, C1c);
    h = pk_fma_vv(u, h, C0c);
    return pk_mul(pc, h);
}

// EKF-form UKF step (exact under Euler + sigma-pair symmetry):
//   x_pred = x + DT*f(x);  P_pred = (I + DT*J) P (I + DT*J)^T + Q
// Single kernel; each block packs its own weight copy into LDS (no d_ws, no
// prep launch). block = 640 threads = 64 elements x 10 waves (role = wave):
//   roles 0-7 : K-loop quarters (f(x) + J partials, packed f16, LDS weights)
//   roles 8-9 : noise-MLP halves (packed f16)
//   role 0 lanes: epilogue (reduce, A P A^T, analytic update, writes)
#define PSTR 259   // per-element partial stride (odd -> conflict-free)
__global__ __launch_bounds__(640) void ukf_main(
    const float* __restrict__ Xh, const float* __restrict__ Pin,
    const float* __restrict__ Uin, const float* __restrict__ Yin,
    const float* __restrict__ W1, const float* __restrict__ b1,
    const float* __restrict__ W2, const float* __restrict__ b2g,
    const float* __restrict__ Wn1, const float* __restrict__ bn1,
    const float* __restrict__ Wq, const float* __restrict__ bqg,
    const float* __restrict__ Wr, const float* __restrict__ brg,
    const float* __restrict__ Hg,
    float* __restrict__ out) {
    __shared__ __align__(16) float swp[64 * 16];  // packed sigma weights
    __shared__ __align__(16) float swn[32 * 16];  // packed noise weights
    __shared__ float part[64 * PSTR];

    const int tid = threadIdx.x;
    const int role = tid >> 6;        // wave-uniform
    const int e = tid & 63;
    const int bb = blockIdx.x * 64 + e;

    // ---- stage 0: per-block weight packing into LDS ----
    if (tid < 64) {
        const int k0 = 2 * tid, k1 = 2 * tid + 1;
        float* o = swp + tid * 16;
#pragma unroll
        for (int i = 0; i < 7; ++i) o[i] = packh2(W1[i * HID + k0], W1[i * HID + k1]);
        o[7] = packh2(b1[k0], b1[k1]);
#pragma unroll
        for (int j = 0; j < 7; ++j) o[8 + j] = packh2(W2[k0 * 7 + j], W2[k1 * 7 + j]);
        o[15] = 0.0f;
    } else if (tid < 96) {
        const int q = tid - 64;
        const int k0 = 2 * q, k1 = 2 * q + 1;
        float* o = swn + q * 16;
#pragma unroll
        for (int i = 0; i < 5; ++i) o[i] = packh2(Wn1[i * NH + k0], Wn1[i * NH + k1]);
        o[5] = packh2(bn1[k0], bn1[k1]);
#pragma unroll
        for (int j = 0; j < 5; ++j) o[6 + j] = packh2(Wq[k0 * 5 + j], Wq[k1 * 5 + j]);
#pragma unroll
        for (int j = 0; j < 4; ++j) o[11 + j] = packh2(Wr[k0 * 4 + j], Wr[k1 * 4 + j]);
        o[15] = 0.0f;
    }

    float x[SD];
#pragma unroll
    for (int i = 0; i < SD; ++i) x[i] = Xh[bb * SD + i];

    __syncthreads();

    if (role < 8) {
        // ---- K-loop slice: pair-rows [4*role, 4*role+4) ----
        const float u0 = Uin[bb * 2 + 0];
        const float u1 = Uin[bb * 2 + 1];
        float zb[7];
#pragma unroll
        for (int i = 0; i < SD; ++i) zb[i] = packh2(x[i], x[i]);
        zb[5] = packh2(u0, u0);
        zb[6] = packh2(u1, u1);
        const float ONE2 = packh2(1.0f, 1.0f);

        float fb[5];                  // packed f-bar partials
        float J2[25];                 // packed J partials, [i*5+j]
#pragma unroll
        for (int i = 0; i < 5; ++i) fb[i] = 0.0f;
#pragma unroll
        for (int t = 0; t < 25; ++t) J2[t] = 0.0f;

        const int pbeg = role << 2;
#pragma unroll
        for (int pp = 0; pp < 4; ++pp) {
            const float* row = swp + ((pbeg + pp) << 4);
            f32x4 wa = *(const f32x4*)(row);        // ds_read_b128, broadcast
            f32x4 wb = *(const f32x4*)(row + 4);
            f32x4 wc = *(const f32x4*)(row + 8);
            f32x4 wd = *(const f32x4*)(row + 12);
            float pre = pk_fma_vv(zb[0], wa.x, wb.w);   // bias in c-operand
            pre = pk_fma_vv(zb[1], wa.y, pre);
            pre = pk_fma_vv(zb[2], wa.z, pre);
            pre = pk_fma_vv(zb[3], wa.w, pre);
            pre = pk_fma_vv(zb[4], wb.x, pre);
            pre = pk_fma_vv(zb[5], wb.y, pre);
            pre = pk_fma_vv(zb[6], wb.z, pre);
            float tt = pk_tanh(pre);
            fb[0] = pk_fma_vv(tt, wc.x, fb[0]);
            fb[1] = pk_fma_vv(tt, wc.y, fb[1]);
            fb[2] = pk_fma_vv(tt, wc.z, fb[2]);
            fb[3] = pk_fma_vv(tt, wc.w, fb[3]);
            fb[4] = pk_fma_vv(tt, wd.x, fb[4]);
            // g = 1 - t^2
            float t2 = pk_mul(tt, tt);
            float g2 = pk_add(ONE2, pk_neg(t2));
            float s0 = pk_mul(g2, wa.x);
            float s1 = pk_mul(g2, wa.y);
            float s2 = pk_mul(g2, wa.z);
            float s3 = pk_mul(g2, wa.w);
            float s4 = pk_mul(g2, wb.x);
            float w2i[5] = { wc.x, wc.y, wc.z, wc.w, wd.x };
#pragma unroll
            for (int i = 0; i < 5; ++i) {
                J2[i * 5 + 0] = pk_fma_vv(s0, w2i[i], J2[i * 5 + 0]);
                J2[i * 5 + 1] = pk_fma_vv(s1, w2i[i], J2[i * 5 + 1]);
                J2[i * 5 + 2] = pk_fma_vv(s2, w2i[i], J2[i * 5 + 2]);
                J2[i * 5 + 3] = pk_fma_vv(s3, w2i[i], J2[i * 5 + 3]);
                J2[i * 5 + 4] = pk_fma_vv(s4, w2i[i], J2[i * 5 + 4]);
            }
        }
        float* o = part + e * PSTR + role * 30;
#pragma unroll
        for (int i = 0; i < 5; ++i) o[i] = fb[i];
#pragma unroll
        for (int t = 0; t < 25; ++t) o[5 + t] = J2[t];
    } else {
        // ---- noise-MLP slice: pair-rows [16w, 16w+16) ----
        const int w = role - 8;
        float xb[5];
#pragma unroll
        for (int i = 0; i < SD; ++i) xb[i] = packh2(x[i], x[i]);
        float gq2[5] = {0.f, 0.f, 0.f, 0.f, 0.f};
        float gr2[4] = {0.f, 0.f, 0.f, 0.f};
        const int pbeg = w << 4;
#pragma unroll 4
        for (int pp = 0; pp < 16; ++pp) {
            const float* row = swn + ((pbeg + pp) << 4);
            f32x4 wa = *(const f32x4*)(row);
            f32x4 wb = *(const f32x4*)(row + 4);
            f32x4 wc = *(const f32x4*)(row + 8);
            f32x4 wd = *(const f32x4*)(row + 12);
            float pre = pk_fma_vv(xb[0], wa.x, wb.y);   // bias pair
            pre = pk_fma_vv(xb[1], wa.y, pre);
            pre = pk_fma_vv(xb[2], wa.z, pre);
            pre = pk_fma_vv(xb[3], wa.w, pre);
            pre = pk_fma_vv(xb[4], wb.x, pre);
            float tt = pk_tanh(pre);
            gq2[0] = pk_fma_vv(tt, wb.z, gq2[0]);
            gq2[1] = pk_fma_vv(tt, wb.w, gq2[1]);
            gq2[2] = pk_fma_vv(tt, wc.x, gq2[2]);
            gq2[3] = pk_fma_vv(tt, wc.y, gq2[3]);
            gq2[4] = pk_fma_vv(tt, wc.z, gq2[4]);
            gr2[0] = pk_fma_vv(tt, wc.w, gr2[0]);
            gr2[1] = pk_fma_vv(tt, wd.x, gr2[1]);
            gr2[2] = pk_fma_vv(tt, wd.y, gr2[2]);
            gr2[3] = pk_fma_vv(tt, wd.z, gr2[3]);
        }
        float* o = part + e * PSTR + 240 + w * 9;
#pragma unroll
        for (int r = 0; r < 5; ++r) o[r] = gq2[r];
#pragma unroll
        for (int r = 0; r < 4; ++r) o[5 + r] = gr2[r];
    }

    __syncthreads();

    // ---------------- epilogue: one lane per element (wave 0) ----------------
    if (tid < 64) {
        const float* pe = part + tid * PSTR;

        float fb2[5], J2[25];
#pragma unroll
        for (int i = 0; i < 5; ++i) fb2[i] = pe[i];
#pragma unroll
        for (int t = 0; t < 25; ++t) J2[t] = pe[5 + t];
#pragma unroll
        for (int r = 1; r < 8; ++r) {
            const float* pr = pe + r * 30;
#pragma unroll
            for (int i = 0; i < 5; ++i) fb2[i] = pk_add(fb2[i], pr[i]);
#pragma unroll
            for (int t = 0; t < 25; ++t) J2[t] = pk_add(J2[t], pr[5 + t]);
        }

        float xp[SD];
#pragma unroll
        for (int i = 0; i < SD; ++i)
            xp[i] = x[i] + DT * (b2g[i] + unpk_lo(fb2[i]) + unpk_hi(fb2[i]));

        // A = I + DT*J
        float A[5][5];
#pragma unroll
        for (int i = 0; i < 5; ++i)
#pragma unroll
            for (int j = 0; j < 5; ++j)
                A[i][j] = ((i == j) ? 1.0f : 0.0f)
                        + DT * (unpk_lo(J2[i * 5 + j]) + unpk_hi(J2[i * 5 + j]));

        // P_pred = A P A^T
        float Pf[5][5];
#pragma unroll
        for (int i = 0; i < 5; ++i)
#pragma unroll
            for (int j = 0; j < 5; ++j) Pf[i][j] = Pin[bb * 25 + i * 5 + j];
        float T[5][5];
#pragma unroll
        for (int i = 0; i < 5; ++i)
#pragma unroll
            for (int l = 0; l < 5; ++l) {
                float v = 0.0f;
#pragma unroll
                for (int j = 0; j < 5; ++j) v = fmaf(A[i][j], Pf[j][l], v);
                T[i][l] = v;
            }
        float Pp[15];
#pragma unroll
        for (int i = 0; i < 5; ++i)
#pragma unroll
            for (int j = 0; j <= i; ++j) {
                float v = 0.0f;
#pragma unroll
                for (int l = 0; l < 5; ++l) v = fmaf(T[i][l], A[j][l], v);
                Pp[IDX(i, j)] = v;
            }

        // reduce noise partials
        float gq[5], gr[4];
#pragma unroll
        for (int r = 0; r < 5; ++r) {
            float s = pk_add(pe[240 + r], pe[240 + 9 + r]);
            gq[r] = bqg[r] + unpk_lo(s) + unpk_hi(s);
        }
#pragma unroll
        for (int r = 0; r < 4; ++r) {
            float s = pk_add(pe[240 + 5 + r], pe[240 + 14 + r]);
            gr[r] = brg[r] + unpk_lo(s) + unpk_hi(s);
        }

        const float ent0 = 7.0946927f + 0.5f * (gq[0] + gq[1] + gq[2] + gq[3] + gq[4]);
        const float logscale = fmaxf(7.1f - ent0, 0.0f) * 0.2f;
        const float entQ = fmaf(2.5f, logscale, ent0);
        const float entR = 5.6757541f + 0.5f * (gr[0] + gr[1] + gr[2] + gr[3]);
        float qd[5], rd[4];
#pragma unroll
        for (int j = 0; j < 5; ++j) qd[j] = fexp(gq[j] + logscale);
#pragma unroll
        for (int j = 0; j < 4; ++j) rd[j] = fexp(gr[j]);

#pragma unroll
        for (int j = 0; j < SD; ++j) Pp[IDX(j, j)] += qd[j];

        // ------- exact linear update: S = H5^T Pp H5 + R, Pxy = Pp H5 -------
        float Hh[7][4];
#pragma unroll
        for (int i = 0; i < 7; ++i)
#pragma unroll
            for (int m = 0; m < 4; ++m) Hh[i][m] = Hg[i * 4 + m];

        const float uu0 = Uin[bb * 2 + 0];
        const float uu1 = Uin[bb * 2 + 1];
        float yv[4];
#pragma unroll
        for (int m = 0; m < 4; ++m) yv[m] = Yin[bb * 4 + m];

        float yh[4];
#pragma unroll
        for (int m = 0; m < 4; ++m) {
            float v = fmaf(uu0, Hh[5][m], uu1 * Hh[6][m]);
#pragma unroll
            for (int i = 0; i < SD; ++i) v = fmaf(xp[i], Hh[i][m], v);
            yh[m] = v;
        }

        float Pxy[5][4];
#pragma unroll
        for (int i = 0; i < SD; ++i)
#pragma unroll
            for (int m = 0; m < 4; ++m) {
                float v = 0.0f;
#pragma unroll
                for (int j = 0; j < SD; ++j) {
                    float pij = (i >= j) ? Pp[IDX(i, j)] : Pp[IDX(j, i)];
                    v = fmaf(pij, Hh[j][m], v);
                }
                Pxy[i][m] = v;
            }

        float Sm[10];
#pragma unroll
        for (int m = 0; m < 4; ++m)
#pragma unroll
            for (int n = 0; n <= m; ++n) {
                float v = 0.0f;
#pragma unroll
                for (int i = 0; i < SD; ++i) v = fmaf(Hh[i][m], Pxy[i][n], v);
                Sm[IDX(m, n)] = v;
            }
#pragma unroll
        for (int m = 0; m < 4; ++m) Sm[IDX(m, m)] += rd[m];

        // Cholesky of S (4x4, packed lower)
        float Ls[10], di[4];
#pragma unroll
        for (int m = 0; m < 4; ++m) {
            float d = Sm[IDX(m, m)];
#pragma unroll
            for (int k = 0; k < m; ++k) { float l = Ls[IDX(m, k)]; d = fmaf(-l, l, d); }
            d = sqrtf(d);
            Ls[IDX(m, m)] = d;
            di[m] = 1.0f / d;
#pragma unroll
            for (int n = m + 1; n < 4; ++n) {
                float v = Sm[IDX(n, m)];
#pragma unroll
                for (int k = 0; k < m; ++k) v = fmaf(-Ls[IDX(n, k)], Ls[IDX(m, k)], v);
                Ls[IDX(n, m)] = v * di[m];
            }
        }

        // K = Pxy S^{-1}
        float K[5][4];
#pragma unroll
        for (int i = 0; i < SD; ++i) {
            float w[4];
#pragma unroll
            for (int m = 0; m < 4; ++m) {
                float v = Pxy[i][m];
#pragma unroll
                for (int k = 0; k < m; ++k) v = fmaf(-Ls[IDX(m, k)], w[k], v);
                w[m] = v * di[m];
            }
#pragma unroll
            for (int m = 3; m >= 0; --m) {
                float v = w[m];
#pragma unroll
                for (int k = m + 1; k < 4; ++k) v = fmaf(-Ls[IDX(k, m)], K[i][k], v);
                K[i][m] = v * di[m];
            }
        }

        float inn[4];
#pragma unroll
        for (int m = 0; m < 4; ++m) inn[m] = yv[m] - yh[m];

        float Xn[5];
#pragma unroll
        for (int i = 0; i < SD; ++i) {
            float v = xp[i];
#pragma unroll
            for (int m = 0; m < 4; ++m) v = fmaf(K[i][m], inn[m], v);
            Xn[i] = v;
        }

        // P_new = Pp - (K S) K^T
        float KS[5][4];
#pragma unroll
        for (int i = 0; i < SD; ++i)
#pragma unroll
            for (int m = 0; m < 4; ++m) {
                float v = 0.0f;
#pragma unroll
                for (int n = 0; n < 4; ++n) {
                    float snm = (n >= m) ? Sm[IDX(n, m)] : Sm[IDX(m, n)];
                    v = fmaf(K[i][n], snm, v);
                }
                KS[i][m] = v;
            }
        float Pn[15];
#pragma unroll
        for (int i = 0; i < SD; ++i)
#pragma unroll
            for (int j = 0; j <= i; ++j) {
                float v = Pp[IDX(i, j)];
#pragma unroll
                for (int m = 0; m < 4; ++m) v = fmaf(-KS[i][m], K[j][m], v);
                Pn[IDX(i, j)] = v;
            }

#pragma unroll
        for (int i = 0; i < SD; ++i) out[bb * SD + i] = Xn[i];
        float* Po = out + B_N * SD + bb * 25;
#pragma unroll
        for (int i = 0; i < SD; ++i)
#pragma unroll
            for (int j = 0; j < SD; ++j)
                Po[i * 5 + j] = (i >= j) ? Pn[IDX(i, j)] : Pn[IDX(j, i)];
        out[B_N * 30 + bb] = entQ;
        out[B_N * 31 + bb] = entR;
    }
}

extern "C" void kernel_launch(void* const* d_in, const int* in_sizes, int n_in,
                              void* d_out, int out_size, void* d_ws, size_t ws_size,
                              hipStream_t stream) {
    const float* Xh  = (const float*)d_in[0];
    const float* P   = (const float*)d_in[1];
    const float* u   = (const float*)d_in[2];
    const float* y   = (const float*)d_in[3];
    const float* W1  = (const float*)d_in[4];
    const float* b1  = (const float*)d_in[5];
    const float* W2  = (const float*)d_in[6];
    const float* b2  = (const float*)d_in[7];
    const float* Wn1 = (const float*)d_in[8];
    const float* bn1 = (const float*)d_in[9];
    const float* Wq  = (const float*)d_in[10];
    const float* bq  = (const float*)d_in[11];
    const float* Wr  = (const float*)d_in[12];
    const float* br  = (const float*)d_in[13];
    const float* Hob = (const float*)d_in[14];

    ukf_main<<<B_N / 64, 640, 0, stream>>>(Xh, P, u, y,
                                           W1, b1, W2, b2,
                                           Wn1, bn1, Wq, bq, Wr, br,
                                           Hob, (float*)d_out);
}